// Round 9
// baseline (7841.946 us; speedup 1.0000x reference)
//
#include <hip/hip_runtime.h>
#include <hip/hip_bf16.h>
#include <hip/hip_fp16.h>

// Problem constants
#define BB 64
#define SS 512
#define HH 512
#define EE 512

typedef _Float16 h2 __attribute__((ext_vector_type(2)));
typedef _Float16 f16x8 __attribute__((ext_vector_type(8)));
typedef float f32x4 __attribute__((ext_vector_type(4)));

static __device__ inline int dot4i8(unsigned int a, unsigned int b, int c) {
#if __has_builtin(__builtin_amdgcn_sdot4)
  return __builtin_amdgcn_sdot4((int)a, (int)b, c, false);
#else
  int s = c;
#pragma unroll
  for (int i = 0; i < 4; ++i) {
    int av = ((int)(a << (24 - 8 * i))) >> 24;
    int bv = ((int)(b << (24 - 8 * i))) >> 24;
    s += av * bv;
  }
  return s;
#endif
}

static __device__ inline float tanhf_fast(float x) {
  float e = __expf(2.0f * x);
  return 1.0f - 2.0f / (e + 1.0f);
}

static __device__ inline f16x8 cvt8(float4 f0, float4 f1) {
  return (f16x8){(_Float16)f0.x, (_Float16)f0.y, (_Float16)f0.z, (_Float16)f0.w,
                 (_Float16)f1.x, (_Float16)f1.y, (_Float16)f1.z, (_Float16)f1.w};
}

// ---------------------------------------------------------------------------
// MFMA GEMM: out[m][n] = sum_k A[m][k]*W[n][k] + bias0[n] + bias1[n]
// (unchanged from round 5)
// ---------------------------------------------------------------------------
template <bool GATHER>
__global__ __launch_bounds__(256) void gemm_mfma(
    const _Float16* __restrict__ Af16, const int* __restrict__ tokens,
    const float* __restrict__ emb, const float* __restrict__ W,
    const float* __restrict__ bias0, const float* __restrict__ bias1,
    float* __restrict__ out) {
  __shared__ f16x8 wlds[128 * 64];  // [n_loc][slot], slot=(k/8)^(n_loc&7); 128KB
  const int tid = threadIdx.x;
  const int mg = blockIdx.x;       // 64 M-groups of 512 rows
  const int n0 = blockIdx.y * 128; // 4 N-groups

  {
    const int n_loc = tid >> 1;  // 0..127
    const int kh = tid & 1;      // k half (256 each)
    const float4* wrow = (const float4*)(W + (long)(n0 + n_loc) * HH + kh * 256);
#pragma unroll
    for (int i = 0; i < 32; ++i) {
      f16x8 v = cvt8(wrow[2 * i], wrow[2 * i + 1]);
      const int slog = kh * 32 + i;
      wlds[n_loc * 64 + (slog ^ (n_loc & 7))] = v;
    }
  }
  __syncthreads();

  const int w = tid >> 6;
  const int l = tid & 63;
  const int lr = l & 15;
  const int cg = l >> 4;

  float bsum[8];
#pragma unroll
  for (int nt = 0; nt < 8; ++nt) {
    const int n = n0 + nt * 16 + lr;
    bsum[nt] = bias0[n] + bias1[n];
  }

  for (int mt = 0; mt < 8; ++mt) {
    const int m0 = mg * 512 + w * 128 + mt * 16;
    const int row = m0 + lr;
    const float* arow_f32 = nullptr;
    const _Float16* arow_f16 = nullptr;
    if constexpr (GATHER) {
      arow_f32 = emb + (long)tokens[row] * EE;
    } else {
      arow_f16 = Af16 + (long)row * HH;
    }

    f32x4 acc[8] = {{0.f, 0.f, 0.f, 0.f}, {0.f, 0.f, 0.f, 0.f},
                    {0.f, 0.f, 0.f, 0.f}, {0.f, 0.f, 0.f, 0.f},
                    {0.f, 0.f, 0.f, 0.f}, {0.f, 0.f, 0.f, 0.f},
                    {0.f, 0.f, 0.f, 0.f}, {0.f, 0.f, 0.f, 0.f}};
#pragma unroll
    for (int kt = 0; kt < 16; ++kt) {
      f16x8 af;
      if constexpr (GATHER) {
        const float4* p = (const float4*)(arow_f32 + kt * 32 + cg * 8);
        af = cvt8(p[0], p[1]);
      } else {
        af = *(const f16x8*)(arow_f16 + kt * 32 + cg * 8);
      }
#pragma unroll
      for (int nt = 0; nt < 8; ++nt) {
        f16x8 bf = wlds[(nt * 16 + lr) * 64 + ((kt * 4 + cg) ^ (lr & 7))];
        acc[nt] = __builtin_amdgcn_mfma_f32_16x16x32_f16(af, bf, acc[nt], 0, 0, 0);
      }
    }
#pragma unroll
    for (int nt = 0; nt < 8; ++nt) {
      const int n = n0 + nt * 16 + lr;
#pragma unroll
      for (int j = 0; j < 4; ++j) {
        const int m = m0 + cg * 4 + j;
        out[(long)m * HH + n] = acc[nt][j] + bsum[nt];
      }
    }
  }
}

// ---------------------------------------------------------------------------
// Recurrence v6: h_t = tanh(xw_t + W_hh h_{t-1}) with int8 W and int8 h.
// Rounds 5-7 invariant: >128 VGPRs of f16 W forced AGPR overflow -> ~200
// phantom VALU moves/thread/step. Fix: per-row int8 quantization. W row =
// 512 x i8 = 128 uint32 VGPRs (fully addressable), inner loop = 128
// v_dot4_i32_i8, i32 accumulate (exact), f32 dequant via per-row scale.
// h in LDS as int8 (512B/buffer, double-buffered): 32 broadcast uint4
// reads/thread/step. One thread per output row; one barrier per step.
// ---------------------------------------------------------------------------
__global__ __launch_bounds__(512, 2) void rec_v6(
    const float* __restrict__ Whh,  // [512][512] f32
    const float* __restrict__ xw,   // [B*S][512] f32
    _Float16* __restrict__ hout     // [B*S][512] f16
) {
  __shared__ __align__(16) signed char hs[2][512];

  const int b = blockIdx.x;
  const int r = threadIdx.x;
  const long base = (long)b * SS;

  // ---- setup: quantize W row r to int8 with per-row scale ----
  unsigned int qw[128];
  float rowscale;
  {
    const float4* wr = (const float4*)(Whh + (long)r * HH);
    float mx = 0.f;
#pragma unroll 8
    for (int i = 0; i < 128; ++i) {
      float4 v = wr[i];
      mx = fmaxf(mx, fmaxf(fmaxf(fabsf(v.x), fabsf(v.y)),
                           fmaxf(fabsf(v.z), fabsf(v.w))));
    }
    const float inv = 127.f / mx;
#pragma unroll 8
    for (int i = 0; i < 128; ++i) {
      float4 v = wr[i];
      int q0 = (int)rintf(v.x * inv);
      int q1 = (int)rintf(v.y * inv);
      int q2 = (int)rintf(v.z * inv);
      int q3 = (int)rintf(v.w * inv);
      qw[i] = (unsigned int)((q0 & 255) | ((q1 & 255) << 8) |
                             ((q2 & 255) << 16) | ((q3 & 255) << 24));
    }
    rowscale = mx / (127.f * 127.f);
  }
  hs[0][r] = 0;  // h_{-1} = 0
  __syncthreads();

  float xwv = xw[base * HH + r];
  float hval_prev = 0.f;

  for (int t = 0; t < SS; ++t) {
    // deferred hout store for t-1 (drains during this step's compute)
    if (t > 0) hout[(base + t - 1) * HH + r] = (_Float16)hval_prev;
    // prefetch next step's xw
    float xw_next = (t + 1 < SS) ? xw[(base + t + 1) * HH + r] : 0.f;

    const uint4* hb = (const uint4*)hs[t & 1];
    int a0 = 0, a1 = 0, a2 = 0, a3 = 0;
#pragma unroll
    for (int j = 0; j < 32; ++j) {
      uint4 u = hb[j];
      a0 = dot4i8(qw[4 * j + 0], u.x, a0);
      a1 = dot4i8(qw[4 * j + 1], u.y, a1);
      a2 = dot4i8(qw[4 * j + 2], u.z, a2);
      a3 = dot4i8(qw[4 * j + 3], u.w, a3);
    }
    const int idot = (a0 + a1) + (a2 + a3);
    float hval = tanhf_fast(xwv + (float)idot * rowscale);

    hs[(t + 1) & 1][r] = (signed char)(int)rintf(hval * 127.f);
    __syncthreads();
    xwv = xw_next;
    hval_prev = hval;
  }
  hout[(base + SS - 1) * HH + r] = (_Float16)hval_prev;
}

// out[m][c] = sum_h h1[m][h] * Wfc[c][h] + bfc[c];  one wave per row m
__global__ __launch_bounds__(256) void fc_kernel(
    const _Float16* __restrict__ h1, const float* __restrict__ Wfc,
    const float* __restrict__ bfc, float* __restrict__ out) {
  const int lane = threadIdx.x & 63;
  const int wid = threadIdx.x >> 6;
  const long m = (long)blockIdx.x * 4 + wid;
  f16x8 hv = ((const f16x8*)(h1 + m * HH))[lane];
  const float4* w0 = (const float4*)(Wfc);
  const float4* w1 = (const float4*)(Wfc + HH);
  float4 a0 = w0[2 * lane], a1 = w0[2 * lane + 1];
  float4 b0 = w1[2 * lane], b1 = w1[2 * lane + 1];
  float p0 = (float)hv[0] * a0.x + (float)hv[1] * a0.y + (float)hv[2] * a0.z +
             (float)hv[3] * a0.w + (float)hv[4] * a1.x + (float)hv[5] * a1.y +
             (float)hv[6] * a1.z + (float)hv[7] * a1.w;
  float p1 = (float)hv[0] * b0.x + (float)hv[1] * b0.y + (float)hv[2] * b0.z +
             (float)hv[3] * b0.w + (float)hv[4] * b1.x + (float)hv[5] * b1.y +
             (float)hv[6] * b1.z + (float)hv[7] * b1.w;
#pragma unroll
  for (int off = 32; off; off >>= 1) {
    p0 += __shfl_down(p0, off);
    p1 += __shfl_down(p1, off);
  }
  if (lane == 0) {
    out[m * 2 + 0] = p0 + bfc[0];
    out[m * 2 + 1] = p1 + bfc[1];
  }
}

extern "C" void kernel_launch(void* const* d_in, const int* in_sizes, int n_in,
                              void* d_out, int out_size, void* d_ws, size_t ws_size,
                              hipStream_t stream) {
  const int* tokens = (const int*)d_in[0];
  const float* emb = (const float*)d_in[1];
  const float* W_ih0 = (const float*)d_in[2];
  const float* b_ih0 = (const float*)d_in[3];
  const float* W_hh0 = (const float*)d_in[4];
  const float* b_hh0 = (const float*)d_in[5];
  const float* W_ih1 = (const float*)d_in[6];
  const float* b_ih1 = (const float*)d_in[7];
  const float* W_hh1 = (const float*)d_in[8];
  const float* b_hh1 = (const float*)d_in[9];
  const float* W_fc = (const float*)d_in[10];
  const float* b_fc = (const float*)d_in[11];
  float* out = (float*)d_out;

  const long MS = (long)BB * SS;                 // 32768
  float* bufA = (float*)d_ws;                    // xw [MS][512] f32 (64MB)
  _Float16* bufB = (_Float16*)(bufA + MS * HH);  // h  [MS][512] f16 (32MB)

  // xw0 = gather(emb, tokens) @ W_ih0^T + b_ih0 + b_hh0
  gemm_mfma<true><<<dim3(64, 4), 256, 0, stream>>>(
      nullptr, tokens, emb, W_ih0, b_ih0, b_hh0, bufA);
  // layer 0 recurrence -> h0 (f16) in bufB
  rec_v6<<<64, 512, 0, stream>>>(W_hh0, bufA, bufB);
  // xw1 = h0 @ W_ih1^T + b_ih1 + b_hh1  (A = h0 f16)
  gemm_mfma<false><<<dim3(64, 4), 256, 0, stream>>>(
      bufB, nullptr, nullptr, W_ih1, b_ih1, b_hh1, bufA);
  // layer 1 recurrence -> h1 (f16) in bufB
  rec_v6<<<64, 512, 0, stream>>>(W_hh1, bufA, bufB);
  // FC
  fc_kernel<<<8192, 256, 0, stream>>>(bufB, W_fc, b_fc, out);
}

// Round 10
// 1352.409 us; speedup vs baseline: 5.7985x; 5.7985x over previous
//
#include <hip/hip_runtime.h>
#include <hip/hip_bf16.h>
#include <hip/hip_fp16.h>

// Problem constants
#define BB 64
#define SS 512
#define HH 512
#define EE 512

typedef _Float16 h2 __attribute__((ext_vector_type(2)));
typedef _Float16 f16x8 __attribute__((ext_vector_type(8)));
typedef float f32x4 __attribute__((ext_vector_type(4)));

static __device__ inline int dot4i8(unsigned int a, unsigned int b, int c) {
#if __has_builtin(__builtin_amdgcn_sdot4)
  return __builtin_amdgcn_sdot4((int)a, (int)b, c, false);
#else
  int s = c;
#pragma unroll
  for (int i = 0; i < 4; ++i) {
    int av = ((int)(a << (24 - 8 * i))) >> 24;
    int bv = ((int)(b << (24 - 8 * i))) >> 24;
    s += av * bv;
  }
  return s;
#endif
}

static __device__ inline float tanhf_fast(float x) {
  float e = __expf(2.0f * x);
  return 1.0f - 2.0f / (e + 1.0f);
}

static __device__ inline f16x8 cvt8(float4 f0, float4 f1) {
  return (f16x8){(_Float16)f0.x, (_Float16)f0.y, (_Float16)f0.z, (_Float16)f0.w,
                 (_Float16)f1.x, (_Float16)f1.y, (_Float16)f1.z, (_Float16)f1.w};
}

// ---------------------------------------------------------------------------
// MFMA GEMM: out[m][n] = sum_k A[m][k]*W[n][k] + bias0[n] + bias1[n]
// (unchanged from round 5)
// ---------------------------------------------------------------------------
template <bool GATHER>
__global__ __launch_bounds__(256) void gemm_mfma(
    const _Float16* __restrict__ Af16, const int* __restrict__ tokens,
    const float* __restrict__ emb, const float* __restrict__ W,
    const float* __restrict__ bias0, const float* __restrict__ bias1,
    float* __restrict__ out) {
  __shared__ f16x8 wlds[128 * 64];  // [n_loc][slot], slot=(k/8)^(n_loc&7); 128KB
  const int tid = threadIdx.x;
  const int mg = blockIdx.x;       // 64 M-groups of 512 rows
  const int n0 = blockIdx.y * 128; // 4 N-groups

  {
    const int n_loc = tid >> 1;  // 0..127
    const int kh = tid & 1;      // k half (256 each)
    const float4* wrow = (const float4*)(W + (long)(n0 + n_loc) * HH + kh * 256);
#pragma unroll
    for (int i = 0; i < 32; ++i) {
      f16x8 v = cvt8(wrow[2 * i], wrow[2 * i + 1]);
      const int slog = kh * 32 + i;
      wlds[n_loc * 64 + (slog ^ (n_loc & 7))] = v;
    }
  }
  __syncthreads();

  const int w = tid >> 6;
  const int l = tid & 63;
  const int lr = l & 15;
  const int cg = l >> 4;

  float bsum[8];
#pragma unroll
  for (int nt = 0; nt < 8; ++nt) {
    const int n = n0 + nt * 16 + lr;
    bsum[nt] = bias0[n] + bias1[n];
  }

  for (int mt = 0; mt < 8; ++mt) {
    const int m0 = mg * 512 + w * 128 + mt * 16;
    const int row = m0 + lr;
    const float* arow_f32 = nullptr;
    const _Float16* arow_f16 = nullptr;
    if constexpr (GATHER) {
      arow_f32 = emb + (long)tokens[row] * EE;
    } else {
      arow_f16 = Af16 + (long)row * HH;
    }

    f32x4 acc[8] = {{0.f, 0.f, 0.f, 0.f}, {0.f, 0.f, 0.f, 0.f},
                    {0.f, 0.f, 0.f, 0.f}, {0.f, 0.f, 0.f, 0.f},
                    {0.f, 0.f, 0.f, 0.f}, {0.f, 0.f, 0.f, 0.f},
                    {0.f, 0.f, 0.f, 0.f}, {0.f, 0.f, 0.f, 0.f}};
#pragma unroll
    for (int kt = 0; kt < 16; ++kt) {
      f16x8 af;
      if constexpr (GATHER) {
        const float4* p = (const float4*)(arow_f32 + kt * 32 + cg * 8);
        af = cvt8(p[0], p[1]);
      } else {
        af = *(const f16x8*)(arow_f16 + kt * 32 + cg * 8);
      }
#pragma unroll
      for (int nt = 0; nt < 8; ++nt) {
        f16x8 bf = wlds[(nt * 16 + lr) * 64 + ((kt * 4 + cg) ^ (lr & 7))];
        acc[nt] = __builtin_amdgcn_mfma_f32_16x16x32_f16(af, bf, acc[nt], 0, 0, 0);
      }
    }
#pragma unroll
    for (int nt = 0; nt < 8; ++nt) {
      const int n = n0 + nt * 16 + lr;
#pragma unroll
      for (int j = 0; j < 4; ++j) {
        const int m = m0 + cg * 4 + j;
        out[(long)m * HH + n] = acc[nt][j] + bsum[nt];
      }
    }
  }
}

// ---------------------------------------------------------------------------
// Recurrence v7: h_t = tanh(xw_t + W_hh h_{t-1}) with int8 W and int8 h.
// v6 failed (VGPR_Count=48): the setup loops used `#pragma unroll 8`,
// leaving a RUNTIME index into qw[] -> whole array demoted to scratch
// (rule #20), 3770us/layer of scratch stalls. v7: FULL unroll on both
// setup loops so every qw index is compile-time constant -> qw lives in
// 128 VGPRs. Inner loop unchanged: 128 v_dot4_i32_i8, i32 accumulate
// (exact), f32 dequant by per-row scale. h int8 in LDS (512B double-
// buffered), 32 broadcast uint4 reads/thread/step, one barrier per step.
// ---------------------------------------------------------------------------
__global__ __launch_bounds__(512, 2) void rec_v7(
    const float* __restrict__ Whh,  // [512][512] f32
    const float* __restrict__ xw,   // [B*S][512] f32
    _Float16* __restrict__ hout     // [B*S][512] f16
) {
  __shared__ __align__(16) signed char hs[2][512];

  const int b = blockIdx.x;
  const int r = threadIdx.x;
  const long base = (long)b * SS;

  // ---- setup: quantize W row r to int8 with per-row scale ----
  unsigned int qw[128];
  float rowscale;
  {
    const float4* wr = (const float4*)(Whh + (long)r * HH);
    float mx = 0.f;
#pragma unroll
    for (int i = 0; i < 128; ++i) {  // FULL unroll: static qw indices
      float4 v = wr[i];
      mx = fmaxf(mx, fmaxf(fmaxf(fabsf(v.x), fabsf(v.y)),
                           fmaxf(fabsf(v.z), fabsf(v.w))));
    }
    const float inv = 127.f / mx;
#pragma unroll
    for (int i = 0; i < 128; ++i) {  // FULL unroll: static qw indices
      float4 v = wr[i];
      int q0 = (int)rintf(v.x * inv);
      int q1 = (int)rintf(v.y * inv);
      int q2 = (int)rintf(v.z * inv);
      int q3 = (int)rintf(v.w * inv);
      qw[i] = (unsigned int)((q0 & 255) | ((q1 & 255) << 8) |
                             ((q2 & 255) << 16) | ((q3 & 255) << 24));
    }
    rowscale = mx / (127.f * 127.f);
  }
  hs[0][r] = 0;  // h_{-1} = 0
  __syncthreads();

  float xwv = xw[base * HH + r];
  float hval_prev = 0.f;

  for (int t = 0; t < SS; ++t) {
    // deferred hout store for t-1 (drains during this step's compute)
    if (t > 0) hout[(base + t - 1) * HH + r] = (_Float16)hval_prev;
    // prefetch next step's xw
    float xw_next = (t + 1 < SS) ? xw[(base + t + 1) * HH + r] : 0.f;

    const uint4* hb = (const uint4*)hs[t & 1];
    int a0 = 0, a1 = 0, a2 = 0, a3 = 0;
#pragma unroll
    for (int j = 0; j < 32; ++j) {
      uint4 u = hb[j];
      a0 = dot4i8(qw[4 * j + 0], u.x, a0);
      a1 = dot4i8(qw[4 * j + 1], u.y, a1);
      a2 = dot4i8(qw[4 * j + 2], u.z, a2);
      a3 = dot4i8(qw[4 * j + 3], u.w, a3);
    }
    const int idot = (a0 + a1) + (a2 + a3);
    float hval = tanhf_fast(xwv + (float)idot * rowscale);

    hs[(t + 1) & 1][r] = (signed char)(int)rintf(hval * 127.f);
    __syncthreads();
    xwv = xw_next;
    hval_prev = hval;
  }
  hout[(base + SS - 1) * HH + r] = (_Float16)hval_prev;
}

// out[m][c] = sum_h h1[m][h] * Wfc[c][h] + bfc[c];  one wave per row m
__global__ __launch_bounds__(256) void fc_kernel(
    const _Float16* __restrict__ h1, const float* __restrict__ Wfc,
    const float* __restrict__ bfc, float* __restrict__ out) {
  const int lane = threadIdx.x & 63;
  const int wid = threadIdx.x >> 6;
  const long m = (long)blockIdx.x * 4 + wid;
  f16x8 hv = ((const f16x8*)(h1 + m * HH))[lane];
  const float4* w0 = (const float4*)(Wfc);
  const float4* w1 = (const float4*)(Wfc + HH);
  float4 a0 = w0[2 * lane], a1 = w0[2 * lane + 1];
  float4 b0 = w1[2 * lane], b1 = w1[2 * lane + 1];
  float p0 = (float)hv[0] * a0.x + (float)hv[1] * a0.y + (float)hv[2] * a0.z +
             (float)hv[3] * a0.w + (float)hv[4] * a1.x + (float)hv[5] * a1.y +
             (float)hv[6] * a1.z + (float)hv[7] * a1.w;
  float p1 = (float)hv[0] * b0.x + (float)hv[1] * b0.y + (float)hv[2] * b0.z +
             (float)hv[3] * b0.w + (float)hv[4] * b1.x + (float)hv[5] * b1.y +
             (float)hv[6] * b1.z + (float)hv[7] * b1.w;
#pragma unroll
  for (int off = 32; off; off >>= 1) {
    p0 += __shfl_down(p0, off);
    p1 += __shfl_down(p1, off);
  }
  if (lane == 0) {
    out[m * 2 + 0] = p0 + bfc[0];
    out[m * 2 + 1] = p1 + bfc[1];
  }
}

extern "C" void kernel_launch(void* const* d_in, const int* in_sizes, int n_in,
                              void* d_out, int out_size, void* d_ws, size_t ws_size,
                              hipStream_t stream) {
  const int* tokens = (const int*)d_in[0];
  const float* emb = (const float*)d_in[1];
  const float* W_ih0 = (const float*)d_in[2];
  const float* b_ih0 = (const float*)d_in[3];
  const float* W_hh0 = (const float*)d_in[4];
  const float* b_hh0 = (const float*)d_in[5];
  const float* W_ih1 = (const float*)d_in[6];
  const float* b_ih1 = (const float*)d_in[7];
  const float* W_hh1 = (const float*)d_in[8];
  const float* b_hh1 = (const float*)d_in[9];
  const float* W_fc = (const float*)d_in[10];
  const float* b_fc = (const float*)d_in[11];
  float* out = (float*)d_out;

  const long MS = (long)BB * SS;                 // 32768
  float* bufA = (float*)d_ws;                    // xw [MS][512] f32 (64MB)
  _Float16* bufB = (_Float16*)(bufA + MS * HH);  // h  [MS][512] f16 (32MB)

  // xw0 = gather(emb, tokens) @ W_ih0^T + b_ih0 + b_hh0
  gemm_mfma<true><<<dim3(64, 4), 256, 0, stream>>>(
      nullptr, tokens, emb, W_ih0, b_ih0, b_hh0, bufA);
  // layer 0 recurrence -> h0 (f16) in bufB
  rec_v7<<<64, 512, 0, stream>>>(W_hh0, bufA, bufB);
  // xw1 = h0 @ W_ih1^T + b_ih1 + b_hh1  (A = h0 f16)
  gemm_mfma<false><<<dim3(64, 4), 256, 0, stream>>>(
      bufB, nullptr, nullptr, W_ih1, b_ih1, b_hh1, bufA);
  // layer 1 recurrence -> h1 (f16) in bufB
  rec_v7<<<64, 512, 0, stream>>>(W_hh1, bufA, bufB);
  // FC
  fc_kernel<<<8192, 256, 0, stream>>>(bufB, W_fc, b_fc, out);
}